// Round 4
// baseline (126.153 us; speedup 1.0000x reference)
//
#include <hip/hip_runtime.h>
#include <math.h>

// Hit-miss transform: out[i][j] = min_{di,dj}(x[i+di][j+dj] - Khit[di][dj])
//                               - max_{di,dj}(x[i+di][j+dj] - Kmiss[di][dj])
// H=W=4096 fp32 input, 5x5 kernels, output 4092x4092 fp32.
//
// R4: back to the proven flat structure (R2-style, no cyclic indexing — R3's
// %6 window went to scratch). Win comes from v_min3/v_max3 inline asm
// (compiler won't fuse fminf chains without nnan) + 2x4 tile (1.5 float4
// loads per output). All array indices are plain unrolled loop vars.

constexpr int KS = 5;
constexpr int WW = 4096;
constexpr int HO = 4092;
constexpr int WO = 4092;
constexpr int CG = WO / 4;    // 1023 column groups
constexpr int RPT = 2;        // output rows per thread (4092 = 2*2046)

__device__ __forceinline__ float min3f(float a, float b, float c) {
    float d;
    asm("v_min3_f32 %0, %1, %2, %3" : "=v"(d) : "v"(a), "v"(b), "v"(c));
    return d;
}
__device__ __forceinline__ float max3f(float a, float b, float c) {
    float d;
    asm("v_max3_f32 %0, %1, %2, %3" : "=v"(d) : "v"(a), "v"(b), "v"(c));
    return d;
}

__global__ __launch_bounds__(256) void hitmiss_kernel(
    const float* __restrict__ x,
    const float* __restrict__ kh,
    const float* __restrict__ km,
    float* __restrict__ out)
{
    const int cg = blockIdx.x * blockDim.x + threadIdx.x;  // column group
    if (cg >= CG) return;
    const int j0 = cg * 4;
    const int r0 = blockIdx.y * RPT;

    // Kernel weights: uniform addresses -> scalar loads.
    float wh[KS * KS], wm[KS * KS];
#pragma unroll
    for (int i = 0; i < KS * KS; ++i) {
        wh[i] = kh[i];
        wm[i] = km[i];
    }

    // Flat window: 6 input rows x 8 cols, loaded up front, constant indices.
    float v[RPT + 4][8];
#pragma unroll
    for (int r = 0; r < RPT + 4; ++r) {
        const float* rp = x + (size_t)(r0 + r) * WW + j0;
        float4 a = *reinterpret_cast<const float4*>(rp);
        float4 b = *reinterpret_cast<const float4*>(rp + 4);
        v[r][0] = a.x; v[r][1] = a.y; v[r][2] = a.z; v[r][3] = a.w;
        v[r][4] = b.x; v[r][5] = b.y; v[r][6] = b.z; v[r][7] = b.w;
    }

#pragma unroll
    for (int orow = 0; orow < RPT; ++orow) {
        float mnA[4], mxA[4], mnP[4], mxP[4];

#pragma unroll
        for (int di = 0; di < KS; ++di) {
#pragma unroll
            for (int dj = 0; dj < KS; ++dj) {
                const int k = di * KS + dj;
                const float h = wh[k];
                const float m = wm[k];
#pragma unroll
                for (int p = 0; p < 4; ++p) {
                    const float t  = v[orow + di][dj + p];
                    const float th = t - h;
                    const float tm = t - m;
                    if (k == 0) {
                        mnA[p] = th; mxA[p] = tm;
                    } else if (k & 1) {
                        mnP[p] = th; mxP[p] = tm;
                    } else {
                        // fold pending + current: 12 min3 + 12 max3 per pixel
                        mnA[p] = min3f(mnA[p], mnP[p], th);
                        mxA[p] = max3f(mxA[p], mxP[p], tm);
                    }
                }
            }
        }

        float4 o;
        o.x = mnA[0] - mxA[0];
        o.y = mnA[1] - mxA[1];
        o.z = mnA[2] - mxA[2];
        o.w = mnA[3] - mxA[3];
        *reinterpret_cast<float4*>(out + (size_t)(r0 + orow) * WO + j0) = o;
    }
}

extern "C" void kernel_launch(void* const* d_in, const int* in_sizes, int n_in,
                              void* d_out, int out_size, void* d_ws, size_t ws_size,
                              hipStream_t stream) {
    const float* x  = (const float*)d_in[0];
    const float* kh = (const float*)d_in[1];
    const float* km = (const float*)d_in[2];
    float* out = (float*)d_out;

    dim3 block(256, 1, 1);
    dim3 grid((CG + 255) / 256, HO / RPT, 1);  // 4 x 2046 blocks
    hipLaunchKernelGGL(hitmiss_kernel, grid, block, 0, stream, x, kh, km, out);
}